// Round 4
// baseline (468.799 us; speedup 1.0000x reference)
//
#include <hip/hip_runtime.h>
#include <hip/hip_bf16.h>

#define NNODES 100000
#define NEDGES 1600000
#define DIM 128
#define EDIM 16

// ---- coarse bucketing for CSR build ----
#define NBKT 256
#define BW 391            // bucket node-range width: 256*391 = 100096 >= NNODES
#define CHUNK 4096        // edges per bscatter block
#define EPT 16            // CHUNK / 256
#define NCHUNK ((NEDGES + CHUNK - 1) / CHUNK)   // 391

// ---- agg grid split: gather blocks + eh-copy blocks ----
#define AGG_BLKS 4096
#define CPY_BLKS 1024

// ---- ws layout (bytes). Total ~13.8 MB ----
#define O_BH     0u          // int[256]       bucket histogram
#define O_BOFS   4096u       // int[257]       bucket offsets (exclusive scan)
#define O_BTAIL  8192u       // int[256]       bucket fill cursors
#define O_W1P    16384u      // ushort[16384]  packed bf16 W1 (32 KB)
#define O_W2P    49152u      // ushort[16384]  packed bf16 W2 (32 KB)
#define O_RP     81920u      // int[NNODES+1]  row_ptr
#define O_DINV   491520u     // float[NNODES]  deg^{-1/2}
#define O_CSR    921600u     // int[NEDGES]    edge sources grouped by dst (6.4 MB)
#define O_EBUF   7340032u    // u32[NEDGES]    bucket-grouped packed records (6.4 MB)

typedef __attribute__((ext_vector_type(8))) short bf16x8;
typedef __attribute__((ext_vector_type(4))) float f32x4;

// round-to-nearest-even f32 -> bf16 (as low 16 bits of return)
__device__ __forceinline__ unsigned rn_bf16(float x) {
    unsigned u = __float_as_uint(x);
    return (u + 0x7FFFu + ((u >> 16) & 1u)) >> 16;
}

// ---------------- CSR build: coarse bucket histogram ----------------
__global__ __launch_bounds__(256) void bhist(const int* __restrict__ dst,
                                             int* __restrict__ bh) {
    __shared__ int s[NBKT];
    s[threadIdx.x] = 0;
    __syncthreads();
    for (int e = blockIdx.x * 256 + threadIdx.x; e < NEDGES; e += gridDim.x * 256)
        atomicAdd(&s[dst[e] / BW], 1);
    __syncthreads();
    atomicAdd(&bh[threadIdx.x], s[threadIdx.x]);
}

__global__ __launch_bounds__(256) void bscan(const int* __restrict__ bh,
                                             int* __restrict__ bofs,
                                             int* __restrict__ btail) {
    __shared__ int s[256];
    const int t = threadIdx.x;
    int v = bh[t];
    s[t] = v;
    __syncthreads();
    for (int off = 1; off < 256; off <<= 1) {
        int x = (t >= off) ? s[t - off] : 0;
        __syncthreads();
        s[t] += x;
        __syncthreads();
    }
    int ex = s[t] - v;
    bofs[t] = ex;
    btail[t] = ex;
    if (t == 255) bofs[256] = s[255];
}

// Scatter edges into bucket-grouped ebuf with LDS-ordered, run-coalesced writes.
// Record: src (17 bits) | dst_local (9 bits) << 17.
__global__ __launch_bounds__(256) void bscatter(const int* __restrict__ src,
                                                const int* __restrict__ dst,
                                                int* __restrict__ btail,
                                                unsigned* __restrict__ ebuf) {
    __shared__ int lcnt[NBKT], lofs[NBKT], lcur[NBKT], gbase[NBKT];
    __shared__ unsigned obuf[CHUNK];
    __shared__ unsigned char qb[CHUNK];
    const int tid = threadIdx.x;
    const int e0 = blockIdx.x * CHUNK;
    const int n = min(CHUNK, NEDGES - e0);

    lcnt[tid] = 0;
    __syncthreads();

    int myb[EPT];
    unsigned myrec[EPT];
#pragma unroll
    for (int k = 0; k < EPT; ++k) {
        int q = k * 256 + tid;
        if (q < n) {
            int e = e0 + q;
            int d = dst[e];
            int bb = d / BW;
            int dl = d - bb * BW;
            myrec[k] = (unsigned)src[e] | ((unsigned)dl << 17);
            myb[k] = bb;
            atomicAdd(&lcnt[bb], 1);
        } else myb[k] = -1;
    }
    __syncthreads();

    const int c = lcnt[tid];
    lofs[tid] = c;
    __syncthreads();
    for (int off = 1; off < 256; off <<= 1) {
        int x = (tid >= off) ? lofs[tid - off] : 0;
        __syncthreads();
        lofs[tid] += x;
        __syncthreads();
    }
    int ex = lofs[tid] - c;
    lofs[tid] = ex;
    lcur[tid] = ex;
    gbase[tid] = atomicAdd(&btail[tid], c);
    __syncthreads();

#pragma unroll
    for (int k = 0; k < EPT; ++k) {
        if (myb[k] >= 0) {
            int p = atomicAdd(&lcur[myb[k]], 1);
            obuf[p] = myrec[k];
            qb[p] = (unsigned char)myb[k];
        }
    }
    __syncthreads();

    for (int q = tid; q < n; q += 256) {
        int bb = qb[q];
        ebuf[gbase[bb] + (q - lofs[bb])] = obuf[q];
    }
}

// One block per bucket: fine histogram + scan in LDS, write rp/dinv, scatter
// src into the bucket's contiguous (L2-resident) csr window.
__global__ __launch_bounds__(256) void csr_build(const unsigned* __restrict__ ebuf,
                                                 const int* __restrict__ bofs,
                                                 int* __restrict__ rp,
                                                 float* __restrict__ dinv,
                                                 int* __restrict__ csr) {
    __shared__ int fcnt[392];
    __shared__ int fcur[392];
    __shared__ int part[49];
    const int b = blockIdx.x, tid = threadIdx.x;
    const int nodebase = b * BW;
    const int nn = min(BW, NNODES - nodebase);
    const int e0 = bofs[b], e1 = bofs[b + 1];

    for (int i = tid; i < 392; i += 256) fcnt[i] = 0;
    __syncthreads();
    for (int q = e0 + tid; q < e1; q += 256)
        atomicAdd(&fcnt[ebuf[q] >> 17], 1);
    __syncthreads();

    if (tid < 49) {
        int s = 0;
#pragma unroll
        for (int k = 0; k < 8; ++k) {
            int idx = 8 * tid + k;
            if (idx < 392) s += fcnt[idx];
        }
        part[tid] = s;
    }
    __syncthreads();
    if (tid == 0) {
        int s = 0;
        for (int k = 0; k < 49; ++k) { int v = part[k]; part[k] = s; s += v; }
    }
    __syncthreads();
    if (tid < 49) {
        int s = part[tid];
#pragma unroll
        for (int k = 0; k < 8; ++k) {
            int idx = 8 * tid + k;
            if (idx < 392) { int v = fcnt[idx]; fcnt[idx] = s; s += v; }
        }
    }
    __syncthreads();

    for (int i = tid; i < nn; i += 256) {
        int deg = fcnt[i + 1] - fcnt[i];
        rp[nodebase + i] = e0 + fcnt[i];
        dinv[nodebase + i] = (deg > 0) ? rsqrtf((float)deg) : 0.0f;
        fcur[i] = fcnt[i];
    }
    if (b == NBKT - 1 && tid == 0) rp[NNODES] = NEDGES;
    __syncthreads();

    for (int q = e0 + tid; q < e1; q += 256) {
        unsigned rec = ebuf[q];
        int dl = rec >> 17;
        int pos = atomicAdd(&fcur[dl], 1);
        csr[e0 + pos] = (int)(rec & 0x1FFFFu);
    }
}

// Pack W (f32 [128][128], row = k, col = j) into bf16 MFMA B-fragment order for
// v_mfma_f32_16x16x32_bf16:
//   frag (t=kstep 0..3, c=coltile 0..7, lane 0..63, i 0..7)
//     -> W[32t + 8*(lane>>4) + i][16c + (lane&15)]
__global__ __launch_bounds__(256) void wpack_kernel(const float* __restrict__ W1,
                                                    const float* __restrict__ W2,
                                                    ushort* __restrict__ w1p,
                                                    ushort* __restrict__ w2p) {
    int idx = blockIdx.x * 256 + threadIdx.x;     // 0..16383
    int i = idx & 7;
    int l = (idx >> 3) & 63;
    int c = (idx >> 9) & 7;
    int t = (idx >> 12) & 3;
    int k = 32 * t + 8 * (l >> 4) + i;
    int j = 16 * c + (l & 15);
    w1p[idx] = (ushort)rn_bf16(W1[k * DIM + j]);
    w2p[idx] = (ushort)rn_bf16(W2[k * DIM + j]);
}

// Gather-aggregate. One wave per node; half-wave (32 lanes x float4) per edge.
// Masked, tail-free main loop: every iteration covers 8 edge slots; slots past
// `end` clamp the csr index to end-1 (L1-hot row) with weight 0 -> no serial
// dependent tail steps. csr words for iteration i+1 are prefetched while
// iteration i's rows are in flight (hides one of the two chained latencies).
// Blocks >= AGG_BLKS do the eh passthrough copy (overlaps the latency-bound
// gather instead of serializing after it).
__global__ __launch_bounds__(256) void agg_kernel(const int* __restrict__ rp,
                                                  const int* __restrict__ csr,
                                                  const float* __restrict__ dinv,
                                                  const float* __restrict__ nh,
                                                  float* __restrict__ agg,
                                                  const float* __restrict__ eh,
                                                  float* __restrict__ out_eh) {
    if (blockIdx.x >= AGG_BLKS) {
        // ---- eh passthrough copy: 6.4M float4 ----
        const float4* s = (const float4*)eh;
        float4* d = (float4*)out_eh;
        const int total = NEDGES * EDIM / 4;
        for (int q = (blockIdx.x - AGG_BLKS) * 256 + threadIdx.x; q < total;
             q += CPY_BLKS * 256)
            d[q] = s[q];
        return;
    }

    const int lane = threadIdx.x & 63;
    const int half = lane >> 5;
    const int l32  = lane & 31;
    const int wid     = (blockIdx.x * 256 + threadIdx.x) >> 6;
    const int nwaves  = (AGG_BLKS * 256) >> 6;

    for (int n = wid; n < NNODES; n += nwaves) {
        const int beg = rp[n];
        const int end = rp[n + 1];
        const float dn = dinv[n];
        float ax = 0.0f, ay = 0.0f, az = 0.0f, aw = 0.0f;

        if (beg < end) {
            const int last = end - 1;
            // prologue: csr words for the first 8-edge window
            int c0 = csr[min(beg + 0 + half, last)];
            int c1 = csr[min(beg + 2 + half, last)];
            int c2 = csr[min(beg + 4 + half, last)];
            int c3 = csr[min(beg + 6 + half, last)];
            for (int i = beg; i < end; i += 8) {
                const int inext = i + 8;
                int p0 = c0, p1 = c1, p2 = c2, p3 = c3;
                if (inext < end) {   // wave-uniform branch
                    p0 = csr[min(inext + 0 + half, last)];
                    p1 = csr[min(inext + 2 + half, last)];
                    p2 = csr[min(inext + 4 + half, last)];
                    p3 = csr[min(inext + 6 + half, last)];
                }
                float w0 = (i + 0 + half < end) ? dinv[c0] : 0.0f;
                float w1 = (i + 2 + half < end) ? dinv[c1] : 0.0f;
                float w2 = (i + 4 + half < end) ? dinv[c2] : 0.0f;
                float w3 = (i + 6 + half < end) ? dinv[c3] : 0.0f;
                float4 f0 = ((const float4*)(nh + (size_t)c0 * DIM))[l32];
                float4 f1 = ((const float4*)(nh + (size_t)c1 * DIM))[l32];
                float4 f2 = ((const float4*)(nh + (size_t)c2 * DIM))[l32];
                float4 f3 = ((const float4*)(nh + (size_t)c3 * DIM))[l32];
                ax = fmaf(f0.x, w0, ax); ay = fmaf(f0.y, w0, ay);
                az = fmaf(f0.z, w0, az); aw = fmaf(f0.w, w0, aw);
                ax = fmaf(f1.x, w1, ax); ay = fmaf(f1.y, w1, ay);
                az = fmaf(f1.z, w1, az); aw = fmaf(f1.w, w1, aw);
                ax = fmaf(f2.x, w2, ax); ay = fmaf(f2.y, w2, ay);
                az = fmaf(f2.z, w2, az); aw = fmaf(f2.w, w2, aw);
                ax = fmaf(f3.x, w3, ax); ay = fmaf(f3.y, w3, ay);
                az = fmaf(f3.z, w3, az); aw = fmaf(f3.w, w3, aw);
                c0 = p0; c1 = p1; c2 = p2; c3 = p3;
            }
        }

        ax += __shfl_xor(ax, 32);
        ay += __shfl_xor(ay, 32);
        az += __shfl_xor(az, 32);
        aw += __shfl_xor(aw, 32);
        if (half == 0) {
            ((float4*)(agg + (size_t)n * DIM))[l32] =
                make_float4(ax * dn, ay * dn, az * dn, aw * dn);
        }
    }
}

// MFMA 2-layer MLP, in-place on x/out (= agg buffer). 512 threads = 8 waves;
// block tile = 128 nodes (wave w owns 16 rows). Weights: bf16 fragments staged
// to LDS (64 KB). Activations: f32 -> hi/lo bf16 split (2 MFMAs) so activation
// precision stays ~f32; only weight bf16 rounding remains.
__global__ __launch_bounds__(512) void mlp_mfma(const float* __restrict__ x,
                                                const ushort* __restrict__ w1p,
                                                const ushort* __restrict__ w2p,
                                                const float* __restrict__ b1,
                                                const float* __restrict__ b2,
                                                float* __restrict__ out) {
    __shared__ __align__(16) ushort sW[2][16384];   // 64 KB: packed W1, W2
    __shared__ __align__(16) float  sH[8][2048];    // 64 KB: per-wave 16x128 f32

    const int tid  = threadIdx.x;
    const int lane = tid & 63;
    const int w    = tid >> 6;
    const int m    = lane & 15;     // A row / C col within tile
    const int g    = lane >> 4;     // k-group / C row-group

    {
        const float4* s1 = (const float4*)w1p;
        const float4* s2 = (const float4*)w2p;
        float4* d1 = (float4*)sW[0];
        float4* d2 = (float4*)sW[1];
        for (int q = tid; q < 2048; q += 512) d1[q] = s1[q];
        for (int q = tid; q < 2048; q += 512) d2[q] = s2[q];
    }

    float bias1[8], bias2[8];
#pragma unroll
    for (int c = 0; c < 8; ++c) { bias1[c] = b1[16 * c + m]; bias2[c] = b2[16 * c + m]; }

    __syncthreads();

    const int rowbase = blockIdx.x * 128 + w * 16;
    char* hbase = (char*)sH[w];
    const int node = rowbase + m;
    const bool valid = (node < NNODES);

    // ---------------- layer 1: acc = X @ W1 ----------------
    f32x4 acc[8];
#pragma unroll
    for (int c = 0; c < 8; ++c) acc[c] = f32x4{0.f, 0.f, 0.f, 0.f};

#pragma unroll
    for (int t = 0; t < 4; ++t) {
        const int kb = 32 * t + 8 * g;
        float4 xa = make_float4(0.f, 0.f, 0.f, 0.f);
        float4 xb = make_float4(0.f, 0.f, 0.f, 0.f);
        if (valid) {
            const float4* px = (const float4*)(x + (size_t)node * DIM + kb);
            xa = px[0];
            xb = px[1];
        }
        float v[8] = {xa.x, xa.y, xa.z, xa.w, xb.x, xb.y, xb.z, xb.w};
        bf16x8 ahi, alo;
#pragma unroll
        for (int i = 0; i < 8; ++i) {
            unsigned hu = rn_bf16(v[i]);
            float hf = __uint_as_float(hu << 16);
            ahi[i] = (short)hu;
            alo[i] = (short)rn_bf16(v[i] - hf);
        }
#pragma unroll
        for (int c = 0; c < 8; ++c) {
            bf16x8 bw = *(const bf16x8*)&sW[0][((t * 8 + c) * 64 + lane) * 8];
            acc[c] = __builtin_amdgcn_mfma_f32_16x16x32_bf16(alo, bw, acc[c], 0, 0, 0);
            acc[c] = __builtin_amdgcn_mfma_f32_16x16x32_bf16(ahi, bw, acc[c], 0, 0, 0);
        }
    }

    // bias + relu -> swizzled sH   (C/D: row = 4g + r, col = 16c + m)
#pragma unroll
    for (int c = 0; c < 8; ++c) {
#pragma unroll
        for (int r = 0; r < 4; ++r) {
            int row = 4 * g + r;
            float hv = fmaxf(acc[c][r] + bias1[c], 0.0f);
            int off = (row * 512 + (16 * c + m) * 4) ^ ((row & 7) << 4);
            *(float*)(hbase + off) = hv;
        }
    }

    // ---------------- layer 2: acc = relu(h) @ W2 ----------------
#pragma unroll
    for (int c = 0; c < 8; ++c) acc[c] = f32x4{0.f, 0.f, 0.f, 0.f};

#pragma unroll
    for (int t = 0; t < 4; ++t) {
        const int kb = 32 * t + 8 * g;
        int o0 = (m * 512 + kb * 4) ^ ((m & 7) << 4);
        int o1 = (m * 512 + kb * 4 + 16) ^ ((m & 7) << 4);
        f32x4 va = *(const f32x4*)(hbase + o0);
        f32x4 vb = *(const f32x4*)(hbase + o1);
        float v[8] = {va[0], va[1], va[2], va[3], vb[0], vb[1], vb[2], vb[3]};
        bf16x8 ahi, alo;
#pragma unroll
        for (int i = 0; i < 8; ++i) {
            unsigned hu = rn_bf16(v[i]);
            float hf = __uint_as_float(hu << 16);
            ahi[i] = (short)hu;
            alo[i] = (short)rn_bf16(v[i] - hf);
        }
#pragma unroll
        for (int c = 0; c < 8; ++c) {
            bf16x8 bw = *(const bf16x8*)&sW[1][((t * 8 + c) * 64 + lane) * 8];
            acc[c] = __builtin_amdgcn_mfma_f32_16x16x32_bf16(alo, bw, acc[c], 0, 0, 0);
            acc[c] = __builtin_amdgcn_mfma_f32_16x16x32_bf16(ahi, bw, acc[c], 0, 0, 0);
        }
    }

    // bias -> swizzled sH, then coalesced f32x4 store
#pragma unroll
    for (int c = 0; c < 8; ++c) {
#pragma unroll
        for (int r = 0; r < 4; ++r) {
            int row = 4 * g + r;
            int off = (row * 512 + (16 * c + m) * 4) ^ ((row & 7) << 4);
            *(float*)(hbase + off) = acc[c][r] + bias2[c];
        }
    }

#pragma unroll
    for (int it = 0; it < 8; ++it) {
        int row = 2 * it + (lane >> 5);
        int c4  = lane & 31;
        int off = (row * 512 + c4 * 16) ^ ((row & 7) << 4);
        f32x4 val = *(const f32x4*)(hbase + off);
        int nodeS = rowbase + row;
        if (nodeS < NNODES)
            *(f32x4*)(out + (size_t)nodeS * DIM + (size_t)c4 * 4) = val;
    }
}

extern "C" void kernel_launch(void* const* d_in, const int* in_sizes, int n_in,
                              void* d_out, int out_size, void* d_ws, size_t ws_size,
                              hipStream_t stream) {
    const float* nh = (const float*)d_in[0];   // f32 [NNODES, DIM]
    const float* eh = (const float*)d_in[1];   // f32 [NEDGES, EDIM]
    const int*   ei = (const int*)d_in[2];     // int32 [2, NEDGES]
    const float* W1 = (const float*)d_in[3];
    const float* b1 = (const float*)d_in[4];
    const float* W2 = (const float*)d_in[5];
    const float* b2 = (const float*)d_in[6];

    char* ws = (char*)d_ws;
    int*      bh    = (int*)(ws + O_BH);
    int*      bofs  = (int*)(ws + O_BOFS);
    int*      btail = (int*)(ws + O_BTAIL);
    ushort*   w1p   = (ushort*)(ws + O_W1P);
    ushort*   w2p   = (ushort*)(ws + O_W2P);
    int*      rp    = (int*)(ws + O_RP);
    float*    dinv  = (float*)(ws + O_DINV);
    int*      csr   = (int*)(ws + O_CSR);
    unsigned* ebuf  = (unsigned*)(ws + O_EBUF);

    float* out_nh = (float*)d_out;
    float* out_eh = out_nh + (size_t)NNODES * DIM;

    const int* src = ei;
    const int* dst = ei + NEDGES;

    hipMemsetAsync(bh, 0, NBKT * sizeof(int), stream);

    bhist<<<256, 256, 0, stream>>>(dst, bh);
    bscan<<<1, 256, 0, stream>>>(bh, bofs, btail);
    wpack_kernel<<<64, 256, 0, stream>>>(W1, W2, w1p, w2p);
    bscatter<<<NCHUNK, 256, 0, stream>>>(src, dst, btail, ebuf);
    csr_build<<<NBKT, 256, 0, stream>>>(ebuf, bofs, rp, dinv, csr);
    agg_kernel<<<AGG_BLKS + CPY_BLKS, 256, 0, stream>>>(rp, csr, dinv, nh, out_nh,
                                                        eh, out_eh);
    mlp_mfma<<<(NNODES + 127) / 128, 512, 0, stream>>>(out_nh, w1p, w2p, b1, b2, out_nh);
}

// Round 5
// 426.802 us; speedup vs baseline: 1.0984x; 1.0984x over previous
//
#include <hip/hip_runtime.h>
#include <hip/hip_bf16.h>
#include <hip/hip_fp16.h>

#define NNODES 100000
#define NEDGES 1600000
#define DIM 128
#define EDIM 16

// ---- coarse bucketing for CSR build ----
#define NBKT 256
#define BW 391            // bucket node-range width: 256*391 = 100096 >= NNODES
#define CHUNK 4096        // edges per bscatter block
#define EPT 16            // CHUNK / 256
#define NCHUNK ((NEDGES + CHUNK - 1) / CHUNK)   // 391

// ---- grid splits ----
#define AGG_BLKS 4096
#define CPY_BLKS 1024
#define HIST_BLKS 256
#define CVT_BLKS 3072

// ---- ws layout (bytes). Total ~39.4 MB ----
#define O_BH     0u          // int[256]       bucket histogram
#define O_BOFS   4096u       // int[257]       bucket offsets (exclusive scan)
#define O_BTAIL  8192u       // int[256]       bucket fill cursors
#define O_W1P    16384u      // ushort[16384]  packed bf16 W1 (32 KB)
#define O_W2P    49152u      // ushort[16384]  packed bf16 W2 (32 KB)
#define O_RP     81920u      // int[NNODES+1]  row_ptr
#define O_DINV   491520u     // float[NNODES]  deg^{-1/2}
#define O_CSR    921600u     // int[NEDGES]    edge sources grouped by dst (6.4 MB)
#define O_EBUF   7340032u    // u32[NEDGES]    bucket-grouped packed records (6.4 MB)
#define O_NHH    13740032u   // f16[NNODES*DIM] converted node features (25.6 MB)

typedef __attribute__((ext_vector_type(8))) short bf16x8;
typedef __attribute__((ext_vector_type(4))) float f32x4;

// round-to-nearest-even f32 -> bf16 (as low 16 bits of return)
__device__ __forceinline__ unsigned rn_bf16(float x) {
    unsigned u = __float_as_uint(x);
    return (u + 0x7FFFu + ((u >> 16) & 1u)) >> 16;
}

// ---------------- bhist + (fused) nh f32->f16 conversion ----------------
__global__ __launch_bounds__(256) void bhist(const int* __restrict__ dst,
                                             int* __restrict__ bh,
                                             const float* __restrict__ nh,
                                             __half* __restrict__ nhh) {
    if (blockIdx.x >= HIST_BLKS) {
        // ---- convert nh (f32) -> nhh (f16), 1.6M uint4 outputs ----
        const float4* s4 = (const float4*)nh;
        uint4* d4 = (uint4*)nhh;
        const int total = NNODES * DIM / 8;
        for (int q = (blockIdx.x - HIST_BLKS) * 256 + threadIdx.x; q < total;
             q += CVT_BLKS * 256) {
            float4 fa = s4[2 * q], fb = s4[2 * q + 1];
            __half2 h0 = __floats2half2_rn(fa.x, fa.y);
            __half2 h1 = __floats2half2_rn(fa.z, fa.w);
            __half2 h2 = __floats2half2_rn(fb.x, fb.y);
            __half2 h3 = __floats2half2_rn(fb.z, fb.w);
            uint4 o;
            o.x = *(const unsigned*)&h0;
            o.y = *(const unsigned*)&h1;
            o.z = *(const unsigned*)&h2;
            o.w = *(const unsigned*)&h3;
            d4[q] = o;
        }
        return;
    }
    __shared__ int s[NBKT];
    s[threadIdx.x] = 0;
    __syncthreads();
    for (int e = blockIdx.x * 256 + threadIdx.x; e < NEDGES; e += HIST_BLKS * 256)
        atomicAdd(&s[dst[e] / BW], 1);
    __syncthreads();
    atomicAdd(&bh[threadIdx.x], s[threadIdx.x]);
}

__global__ __launch_bounds__(256) void bscan(const int* __restrict__ bh,
                                             int* __restrict__ bofs,
                                             int* __restrict__ btail) {
    __shared__ int s[256];
    const int t = threadIdx.x;
    int v = bh[t];
    s[t] = v;
    __syncthreads();
    for (int off = 1; off < 256; off <<= 1) {
        int x = (t >= off) ? s[t - off] : 0;
        __syncthreads();
        s[t] += x;
        __syncthreads();
    }
    int ex = s[t] - v;
    bofs[t] = ex;
    btail[t] = ex;
    if (t == 255) bofs[256] = s[255];
}

// Scatter edges into bucket-grouped ebuf with LDS-ordered, run-coalesced writes.
// Record: src (17 bits) | dst_local (9 bits) << 17.
__global__ __launch_bounds__(256) void bscatter(const int* __restrict__ src,
                                                const int* __restrict__ dst,
                                                int* __restrict__ btail,
                                                unsigned* __restrict__ ebuf) {
    __shared__ int lcnt[NBKT], lofs[NBKT], lcur[NBKT], gbase[NBKT];
    __shared__ unsigned obuf[CHUNK];
    __shared__ unsigned char qb[CHUNK];
    const int tid = threadIdx.x;
    const int e0 = blockIdx.x * CHUNK;
    const int n = min(CHUNK, NEDGES - e0);

    lcnt[tid] = 0;
    __syncthreads();

    int myb[EPT];
    unsigned myrec[EPT];
#pragma unroll
    for (int k = 0; k < EPT; ++k) {
        int q = k * 256 + tid;
        if (q < n) {
            int e = e0 + q;
            int d = dst[e];
            int bb = d / BW;
            int dl = d - bb * BW;
            myrec[k] = (unsigned)src[e] | ((unsigned)dl << 17);
            myb[k] = bb;
            atomicAdd(&lcnt[bb], 1);
        } else myb[k] = -1;
    }
    __syncthreads();

    const int c = lcnt[tid];
    lofs[tid] = c;
    __syncthreads();
    for (int off = 1; off < 256; off <<= 1) {
        int x = (tid >= off) ? lofs[tid - off] : 0;
        __syncthreads();
        lofs[tid] += x;
        __syncthreads();
    }
    int ex = lofs[tid] - c;
    lofs[tid] = ex;
    lcur[tid] = ex;
    gbase[tid] = atomicAdd(&btail[tid], c);
    __syncthreads();

#pragma unroll
    for (int k = 0; k < EPT; ++k) {
        if (myb[k] >= 0) {
            int p = atomicAdd(&lcur[myb[k]], 1);
            obuf[p] = myrec[k];
            qb[p] = (unsigned char)myb[k];
        }
    }
    __syncthreads();

    for (int q = tid; q < n; q += 256) {
        int bb = qb[q];
        ebuf[gbase[bb] + (q - lofs[bb])] = obuf[q];
    }
}

// One block per bucket: fine histogram + scan in LDS, write rp/dinv, scatter
// src into the bucket's contiguous (L2-resident) csr window.
__global__ __launch_bounds__(256) void csr_build(const unsigned* __restrict__ ebuf,
                                                 const int* __restrict__ bofs,
                                                 int* __restrict__ rp,
                                                 float* __restrict__ dinv,
                                                 int* __restrict__ csr) {
    __shared__ int fcnt[392];
    __shared__ int fcur[392];
    __shared__ int part[49];
    const int b = blockIdx.x, tid = threadIdx.x;
    const int nodebase = b * BW;
    const int nn = min(BW, NNODES - nodebase);
    const int e0 = bofs[b], e1 = bofs[b + 1];

    for (int i = tid; i < 392; i += 256) fcnt[i] = 0;
    __syncthreads();
    for (int q = e0 + tid; q < e1; q += 256)
        atomicAdd(&fcnt[ebuf[q] >> 17], 1);
    __syncthreads();

    if (tid < 49) {
        int s = 0;
#pragma unroll
        for (int k = 0; k < 8; ++k) {
            int idx = 8 * tid + k;
            if (idx < 392) s += fcnt[idx];
        }
        part[tid] = s;
    }
    __syncthreads();
    if (tid == 0) {
        int s = 0;
        for (int k = 0; k < 49; ++k) { int v = part[k]; part[k] = s; s += v; }
    }
    __syncthreads();
    if (tid < 49) {
        int s = part[tid];
#pragma unroll
        for (int k = 0; k < 8; ++k) {
            int idx = 8 * tid + k;
            if (idx < 392) { int v = fcnt[idx]; fcnt[idx] = s; s += v; }
        }
    }
    __syncthreads();

    for (int i = tid; i < nn; i += 256) {
        int deg = fcnt[i + 1] - fcnt[i];
        rp[nodebase + i] = e0 + fcnt[i];
        dinv[nodebase + i] = (deg > 0) ? rsqrtf((float)deg) : 0.0f;
        fcur[i] = fcnt[i];
    }
    if (b == NBKT - 1 && tid == 0) rp[NNODES] = NEDGES;
    __syncthreads();

    for (int q = e0 + tid; q < e1; q += 256) {
        unsigned rec = ebuf[q];
        int dl = rec >> 17;
        int pos = atomicAdd(&fcur[dl], 1);
        csr[e0 + pos] = (int)(rec & 0x1FFFFu);
    }
}

// Pack W (f32 [128][128], row = k, col = j) into bf16 MFMA B-fragment order for
// v_mfma_f32_16x16x32_bf16:
//   frag (t=kstep 0..3, c=coltile 0..7, lane 0..63, i 0..7)
//     -> W[32t + 8*(lane>>4) + i][16c + (lane&15)]
__global__ __launch_bounds__(256) void wpack_kernel(const float* __restrict__ W1,
                                                    const float* __restrict__ W2,
                                                    ushort* __restrict__ w1p,
                                                    ushort* __restrict__ w2p) {
    int idx = blockIdx.x * 256 + threadIdx.x;     // 0..16383
    int i = idx & 7;
    int l = (idx >> 3) & 63;
    int c = (idx >> 9) & 7;
    int t = (idx >> 12) & 3;
    int k = 32 * t + 8 * (l >> 4) + i;
    int j = 16 * c + (l & 15);
    w1p[idx] = (ushort)rn_bf16(W1[k * DIM + j]);
    w2p[idx] = (ushort)rn_bf16(W2[k * DIM + j]);
}

// Gather-aggregate from the f16 table (256 B rows -> half the gather traffic).
// One wave per node; QUARTER-wave (16 lanes x 16 B = 8 f16) per row. Each loop
// body covers 8 edge slots (quarter q handles i+q and i+4+q), clamp+zero-weight
// masking for the tail. f32 accumulation (8 regs/lane); cross-quarter reduce
// via shfl_xor(16/32). Blocks >= AGG_BLKS do the eh passthrough copy.
__global__ __launch_bounds__(256) void agg_kernel(const int* __restrict__ rp,
                                                  const int* __restrict__ csr,
                                                  const float* __restrict__ dinv,
                                                  const __half* __restrict__ nhh,
                                                  float* __restrict__ agg,
                                                  const float* __restrict__ eh,
                                                  float* __restrict__ out_eh) {
    if (blockIdx.x >= AGG_BLKS) {
        const float4* s = (const float4*)eh;
        float4* d = (float4*)out_eh;
        const int total = NEDGES * EDIM / 4;
        for (int q = (blockIdx.x - AGG_BLKS) * 256 + threadIdx.x; q < total;
             q += CPY_BLKS * 256)
            d[q] = s[q];
        return;
    }

    const int lane = threadIdx.x & 63;
    const int q    = lane >> 4;       // quarter 0..3
    const int l16  = lane & 15;       // 16-byte slot within the 256 B row
    const int wid     = (blockIdx.x * 256 + threadIdx.x) >> 6;
    const int nwaves  = (AGG_BLKS * 256) >> 6;

    for (int n = wid; n < NNODES; n += nwaves) {
        const int beg = rp[n];
        const int end = rp[n + 1];
        const float dn = dinv[n];
        float a0 = 0.f, a1 = 0.f, a2 = 0.f, a3 = 0.f;
        float a4 = 0.f, a5 = 0.f, a6 = 0.f, a7 = 0.f;

        if (beg < end) {
            const int last = end - 1;
            for (int i = beg; i < end; i += 8) {
                const int eA = i + q, eB = i + 4 + q;
                int ca = csr[min(eA, last)];
                int cb = csr[min(eB, last)];
                float wa = (eA < end) ? dinv[ca] : 0.0f;
                float wb = (eB < end) ? dinv[cb] : 0.0f;
                uint4 ra = ((const uint4*)(nhh + (size_t)ca * DIM))[l16];
                uint4 rb = ((const uint4*)(nhh + (size_t)cb * DIM))[l16];
                float2 f;
                f = __half22float2(*(const __half2*)&ra.x);
                a0 = fmaf(f.x, wa, a0); a1 = fmaf(f.y, wa, a1);
                f = __half22float2(*(const __half2*)&ra.y);
                a2 = fmaf(f.x, wa, a2); a3 = fmaf(f.y, wa, a3);
                f = __half22float2(*(const __half2*)&ra.z);
                a4 = fmaf(f.x, wa, a4); a5 = fmaf(f.y, wa, a5);
                f = __half22float2(*(const __half2*)&ra.w);
                a6 = fmaf(f.x, wa, a6); a7 = fmaf(f.y, wa, a7);
                f = __half22float2(*(const __half2*)&rb.x);
                a0 = fmaf(f.x, wb, a0); a1 = fmaf(f.y, wb, a1);
                f = __half22float2(*(const __half2*)&rb.y);
                a2 = fmaf(f.x, wb, a2); a3 = fmaf(f.y, wb, a3);
                f = __half22float2(*(const __half2*)&rb.z);
                a4 = fmaf(f.x, wb, a4); a5 = fmaf(f.y, wb, a5);
                f = __half22float2(*(const __half2*)&rb.w);
                a6 = fmaf(f.x, wb, a6); a7 = fmaf(f.y, wb, a7);
            }
        }

        // reduce across the 4 quarters (lanes l, l^16, l^32, l^48)
        a0 += __shfl_xor(a0, 16); a0 += __shfl_xor(a0, 32);
        a1 += __shfl_xor(a1, 16); a1 += __shfl_xor(a1, 32);
        a2 += __shfl_xor(a2, 16); a2 += __shfl_xor(a2, 32);
        a3 += __shfl_xor(a3, 16); a3 += __shfl_xor(a3, 32);
        a4 += __shfl_xor(a4, 16); a4 += __shfl_xor(a4, 32);
        a5 += __shfl_xor(a5, 16); a5 += __shfl_xor(a5, 32);
        a6 += __shfl_xor(a6, 16); a6 += __shfl_xor(a6, 32);
        a7 += __shfl_xor(a7, 16); a7 += __shfl_xor(a7, 32);

        if (lane < 16) {
            float4* dst = (float4*)(agg + (size_t)n * DIM + (size_t)l16 * 8);
            dst[0] = make_float4(a0 * dn, a1 * dn, a2 * dn, a3 * dn);
            dst[1] = make_float4(a4 * dn, a5 * dn, a6 * dn, a7 * dn);
        }
    }
}

// MFMA 2-layer MLP, in-place on x/out (= agg buffer). 512 threads = 8 waves;
// block tile = 128 nodes (wave w owns 16 rows). Weights: bf16 fragments staged
// to LDS (64 KB). Activations: f32 -> hi/lo bf16 split (2 MFMAs) so activation
// precision stays ~f32; only weight bf16 rounding remains.
__global__ __launch_bounds__(512) void mlp_mfma(const float* __restrict__ x,
                                                const ushort* __restrict__ w1p,
                                                const ushort* __restrict__ w2p,
                                                const float* __restrict__ b1,
                                                const float* __restrict__ b2,
                                                float* __restrict__ out) {
    __shared__ __align__(16) ushort sW[2][16384];   // 64 KB: packed W1, W2
    __shared__ __align__(16) float  sH[8][2048];    // 64 KB: per-wave 16x128 f32

    const int tid  = threadIdx.x;
    const int lane = tid & 63;
    const int w    = tid >> 6;
    const int m    = lane & 15;     // A row / C col within tile
    const int g    = lane >> 4;     // k-group / C row-group

    {
        const float4* s1 = (const float4*)w1p;
        const float4* s2 = (const float4*)w2p;
        float4* d1 = (float4*)sW[0];
        float4* d2 = (float4*)sW[1];
        for (int q = tid; q < 2048; q += 512) d1[q] = s1[q];
        for (int q = tid; q < 2048; q += 512) d2[q] = s2[q];
    }

    float bias1[8], bias2[8];
#pragma unroll
    for (int c = 0; c < 8; ++c) { bias1[c] = b1[16 * c + m]; bias2[c] = b2[16 * c + m]; }

    __syncthreads();

    const int rowbase = blockIdx.x * 128 + w * 16;
    char* hbase = (char*)sH[w];
    const int node = rowbase + m;
    const bool valid = (node < NNODES);

    // ---------------- layer 1: acc = X @ W1 ----------------
    f32x4 acc[8];
#pragma unroll
    for (int c = 0; c < 8; ++c) acc[c] = f32x4{0.f, 0.f, 0.f, 0.f};

#pragma unroll
    for (int t = 0; t < 4; ++t) {
        const int kb = 32 * t + 8 * g;
        float4 xa = make_float4(0.f, 0.f, 0.f, 0.f);
        float4 xb = make_float4(0.f, 0.f, 0.f, 0.f);
        if (valid) {
            const float4* px = (const float4*)(x + (size_t)node * DIM + kb);
            xa = px[0];
            xb = px[1];
        }
        float v[8] = {xa.x, xa.y, xa.z, xa.w, xb.x, xb.y, xb.z, xb.w};
        bf16x8 ahi, alo;
#pragma unroll
        for (int i = 0; i < 8; ++i) {
            unsigned hu = rn_bf16(v[i]);
            float hf = __uint_as_float(hu << 16);
            ahi[i] = (short)hu;
            alo[i] = (short)rn_bf16(v[i] - hf);
        }
#pragma unroll
        for (int c = 0; c < 8; ++c) {
            bf16x8 bw = *(const bf16x8*)&sW[0][((t * 8 + c) * 64 + lane) * 8];
            acc[c] = __builtin_amdgcn_mfma_f32_16x16x32_bf16(alo, bw, acc[c], 0, 0, 0);
            acc[c] = __builtin_amdgcn_mfma_f32_16x16x32_bf16(ahi, bw, acc[c], 0, 0, 0);
        }
    }

    // bias + relu -> swizzled sH   (C/D: row = 4g + r, col = 16c + m)
#pragma unroll
    for (int c = 0; c < 8; ++c) {
#pragma unroll
        for (int r = 0; r < 4; ++r) {
            int row = 4 * g + r;
            float hv = fmaxf(acc[c][r] + bias1[c], 0.0f);
            int off = (row * 512 + (16 * c + m) * 4) ^ ((row & 7) << 4);
            *(float*)(hbase + off) = hv;
        }
    }

    // ---------------- layer 2: acc = relu(h) @ W2 ----------------
#pragma unroll
    for (int c = 0; c < 8; ++c) acc[c] = f32x4{0.f, 0.f, 0.f, 0.f};

#pragma unroll
    for (int t = 0; t < 4; ++t) {
        const int kb = 32 * t + 8 * g;
        int o0 = (m * 512 + kb * 4) ^ ((m & 7) << 4);
        int o1 = (m * 512 + kb * 4 + 16) ^ ((m & 7) << 4);
        f32x4 va = *(const f32x4*)(hbase + o0);
        f32x4 vb = *(const f32x4*)(hbase + o1);
        float v[8] = {va[0], va[1], va[2], va[3], vb[0], vb[1], vb[2], vb[3]};
        bf16x8 ahi, alo;
#pragma unroll
        for (int i = 0; i < 8; ++i) {
            unsigned hu = rn_bf16(v[i]);
            float hf = __uint_as_float(hu << 16);
            ahi[i] = (short)hu;
            alo[i] = (short)rn_bf16(v[i] - hf);
        }
#pragma unroll
        for (int c = 0; c < 8; ++c) {
            bf16x8 bw = *(const bf16x8*)&sW[1][((t * 8 + c) * 64 + lane) * 8];
            acc[c] = __builtin_amdgcn_mfma_f32_16x16x32_bf16(alo, bw, acc[c], 0, 0, 0);
            acc[c] = __builtin_amdgcn_mfma_f32_16x16x32_bf16(ahi, bw, acc[c], 0, 0, 0);
        }
    }

    // bias -> swizzled sH, then coalesced f32x4 store
#pragma unroll
    for (int c = 0; c < 8; ++c) {
#pragma unroll
        for (int r = 0; r < 4; ++r) {
            int row = 4 * g + r;
            int off = (row * 512 + (16 * c + m) * 4) ^ ((row & 7) << 4);
            *(float*)(hbase + off) = acc[c][r] + bias2[c];
        }
    }

#pragma unroll
    for (int it = 0; it < 8; ++it) {
        int row = 2 * it + (lane >> 5);
        int c4  = lane & 31;
        int off = (row * 512 + c4 * 16) ^ ((row & 7) << 4);
        f32x4 val = *(const f32x4*)(hbase + off);
        int nodeS = rowbase + row;
        if (nodeS < NNODES)
            *(f32x4*)(out + (size_t)nodeS * DIM + (size_t)c4 * 4) = val;
    }
}

extern "C" void kernel_launch(void* const* d_in, const int* in_sizes, int n_in,
                              void* d_out, int out_size, void* d_ws, size_t ws_size,
                              hipStream_t stream) {
    const float* nh = (const float*)d_in[0];   // f32 [NNODES, DIM]
    const float* eh = (const float*)d_in[1];   // f32 [NEDGES, EDIM]
    const int*   ei = (const int*)d_in[2];     // int32 [2, NEDGES]
    const float* W1 = (const float*)d_in[3];
    const float* b1 = (const float*)d_in[4];
    const float* W2 = (const float*)d_in[5];
    const float* b2 = (const float*)d_in[6];

    char* ws = (char*)d_ws;
    int*      bh    = (int*)(ws + O_BH);
    int*      bofs  = (int*)(ws + O_BOFS);
    int*      btail = (int*)(ws + O_BTAIL);
    ushort*   w1p   = (ushort*)(ws + O_W1P);
    ushort*   w2p   = (ushort*)(ws + O_W2P);
    int*      rp    = (int*)(ws + O_RP);
    float*    dinv  = (float*)(ws + O_DINV);
    int*      csr   = (int*)(ws + O_CSR);
    unsigned* ebuf  = (unsigned*)(ws + O_EBUF);
    __half*   nhh   = (__half*)(ws + O_NHH);

    float* out_nh = (float*)d_out;
    float* out_eh = out_nh + (size_t)NNODES * DIM;

    const int* src = ei;
    const int* dst = ei + NEDGES;

    hipMemsetAsync(bh, 0, NBKT * sizeof(int), stream);

    bhist<<<HIST_BLKS + CVT_BLKS, 256, 0, stream>>>(dst, bh, nh, nhh);
    bscan<<<1, 256, 0, stream>>>(bh, bofs, btail);
    wpack_kernel<<<64, 256, 0, stream>>>(W1, W2, w1p, w2p);
    bscatter<<<NCHUNK, 256, 0, stream>>>(src, dst, btail, ebuf);
    csr_build<<<NBKT, 256, 0, stream>>>(ebuf, bofs, rp, dinv, csr);
    agg_kernel<<<AGG_BLKS + CPY_BLKS, 256, 0, stream>>>(rp, csr, dinv, nhh, out_nh,
                                                        eh, out_eh);
    mlp_mfma<<<(NNODES + 127) / 128, 512, 0, stream>>>(out_nh, w1p, w2p, b1, b2, out_nh);
}